// Round 4
// baseline (2680.996 us; speedup 1.0000x reference)
//
#include <hip/hip_runtime.h>

#define NXN 96            // nodes per side
#define NNODE (NXN*NXN)   // 9216
#define NCW 95            // cells per side
#define NTHREADS 1024
#define NWAVES (NTHREADS/64)
#define MAXIT 4000
#define TOL_REL 1e-6

__device__ __forceinline__ void dual_warp_red(double& a, double& b){
  #pragma unroll
  for (int off = 32; off > 0; off >>= 1){
    a += __shfl_down(a, off, 64);   // two independent chains overlap
    b += __shfl_down(b, off, 64);
  }
}

__device__ __forceinline__ double sum16_tree(const double* buf){
  double t0 = buf[0]  + buf[1],  t1 = buf[2]  + buf[3];
  double t2 = buf[4]  + buf[5],  t3 = buf[6]  + buf[7];
  double t4 = buf[8]  + buf[9],  t5 = buf[10] + buf[11];
  double t6 = buf[12] + buf[13], t7 = buf[14] + buf[15];
  double u0 = t0 + t1, u1 = t2 + t3, u2 = t4 + t5, u3 = t6 + t7;
  return (u0 + u1) + (u2 + u3);
}

__global__ __launch_bounds__(NTHREADS, 1)
void fem_cg_kernel(const float* __restrict__ mask, float* __restrict__ out){
  __shared__ float  s_buf0[NNODE];       // publish buffers, parity-alternated
  __shared__ float  s_buf1[NNODE];
  __shared__ double s_gA[2][NWAVES];     // parity-alternated partials
  __shared__ double s_gB[2][NWAVES];
  const int tid = threadIdx.x, lane = tid & 63, wid = tid >> 6;
  const int bx = tid & 31, by = tid >> 5;    // 32x32 thread grid
  const int i0 = 3*bx, j0 = 3*by;            // each thread owns 3x3 nodes

  // Persistent sigma window: S[a][b] = sigma(cell i0-1+a, j0-1+b), 0 outside.
  float S[4][4];
  #pragma unroll
  for (int a = 0; a < 4; a++)
    #pragma unroll
    for (int b = 0; b < 4; b++){
      int ci = i0-1+a, cj = j0-1+b;
      float m = 0.f;
      if (ci >= 0 && ci < NCW && cj >= 0 && cj < NCW)
        m = 0.001f + 0.999f * mask[cj*NCW + ci];
      S[a][b] = m;
    }

  // Jacobi inverse-diagonal (0 on Dirichlet rows: i==0 or i==95)
  float invd[3][3];
  #pragma unroll
  for (int di = 0; di < 3; di++)
    #pragma unroll
    for (int dj = 0; dj < 3; dj++){
      float s00 = S[di+1][dj+1], sW = S[di][dj+1], sS = S[di+1][dj], sWS = S[di][dj];
      float cD = s00 + 3.f*sW + sS + sWS;
      bool isbc = (i0+di == 0) || (i0+di == NXN-1);
      invd[di][dj] = isbc ? 0.f : 1.f/cD;
    }

  // 7-point stencil apply on a 5x5 window (row i BC-masked)
  // coefficients: C*W[c], E*W[E], W*W[W], N, S, NW, SE  (see derivation R0)
  #define STENCIL(Wm, di, dj, dst)                                          \
    {                                                                        \
      int i_ = i0+(di);                                                      \
      bool isbc_ = (i_ == 0) || (i_ == NXN-1);                               \
      float s00 = S[(di)+1][(dj)+1], sW = S[(di)][(dj)+1];                   \
      float sS  = S[(di)+1][(dj)],   sWS = S[(di)][(dj)];                    \
      float v_ = (s00 + 3.f*sW + sS + sWS)*Wm[(di)+1][(dj)+1]                \
               + 0.5f*(sS - s00)*Wm[(di)+2][(dj)+1]                          \
               + 0.5f*(sWS - sW)*Wm[(di)][(dj)+1]                            \
               - 0.5f*(s00 + 3.f*sW)*Wm[(di)+1][(dj)+2]                      \
               - 0.5f*(sS + 3.f*sWS)*Wm[(di)+1][(dj)]                        \
               - sW*Wm[(di)][(dj)+2]                                         \
               - sS*Wm[(di)+2][(dj)];                                        \
      dst = isbc_ ? 0.f : v_;                                                \
    }

  // ---- init: warm start u0lin = 1 - i/95 (exact BC); r0 = -(A u0lin) ----
  float x[3][3], r[3][3], w[3][3], z[3][3], s[3][3], p[3][3];
  #pragma unroll
  for (int di = 0; di < 3; di++)
    #pragma unroll
    for (int dj = 0; dj < 3; dj++){
      x[di][dj] = 0.f; z[di][dj] = 0.f; s[di][dj] = 0.f; p[di][dj] = 0.f;
      int i = i0+di;
      float s00 = S[di+1][dj+1], sW = S[di][dj+1], sS = S[di+1][dj], sWS = S[di][dj];
      float uc = 1.f - (float)i     * (1.f/95.f);
      float uE = 1.f - (float)(i+1) * (1.f/95.f);
      float uW = 1.f - (float)(i-1) * (1.f/95.f);
      float v = (s00 + 3.f*sW + sS + sWS)*uc
              + 0.5f*(sS - s00)*uE
              + 0.5f*(sWS - sW)*uW
              - 0.5f*(s00 + 3.f*sW)*uc
              - 0.5f*(sS + 3.f*sWS)*uc
              - sW*uW
              - sS*uE;
      bool isbc = (i == 0) || (i == NXN-1);
      float rv = isbc ? 0.f : -v;
      r[di][dj] = rv;
      float uv = rv * invd[di][dj];            // u0 = M r0
      s_buf1[(j0+dj)*NXN + i] = uv;            // publish u0 (buf1)
    }
  __syncthreads();

  // w0 = A u0
  {
    float Wm[5][5];
    #pragma unroll
    for (int a = 0; a < 5; a++)
      #pragma unroll
      for (int b = 0; b < 5; b++){
        int gi = i0-1+a, gj = j0-1+b;
        Wm[a][b] = (gi >= 0 && gi < NXN && gj >= 0 && gj < NXN) ? s_buf1[gj*NXN + gi] : 0.f;
      }
    #pragma unroll
    for (int di = 0; di < 3; di++)
      #pragma unroll
      for (int dj = 0; dj < 3; dj++)
        STENCIL(Wm, di, dj, w[di][dj]);
  }

  double gamma_old = 1.0, alpha_old = 1.0, tol = 0.0;

  // ---- pipelined PCG (Ghysels-Vanroose): ONE barrier per iteration ----
  for (int it = 0; it < MAXIT; ++it){
    float* pub = (it & 1) ? s_buf1 : s_buf0;

    // m = M w ; publish; local dots gamma=r.u, delta=w.u (u = invd*r)
    float m[3][3];
    double gp = 0.0, dp = 0.0;
    #pragma unroll
    for (int di = 0; di < 3; di++)
      #pragma unroll
      for (int dj = 0; dj < 3; dj++){
        float mv = invd[di][dj] * w[di][dj];
        m[di][dj] = mv;
        pub[(j0+dj)*NXN + (i0+di)] = mv;
        double uv = (double)(invd[di][dj] * r[di][dj]);
        gp += (double)r[di][dj] * uv;
        dp += (double)w[di][dj] * uv;
      }
    dual_warp_red(gp, dp);
    if (lane == 0){ s_gA[it&1][wid] = gp; s_gB[it&1][wid] = dp; }
    __syncthreads();                       // publishes m AND partials

    // matvec n = A m (halo from pub) — overlaps the sum16 below via ILP
    float n[3][3];
    {
      float Wm[5][5];
      #pragma unroll
      for (int a = 0; a < 5; a++)
        #pragma unroll
        for (int b = 0; b < 5; b++){
          if (a >= 1 && a <= 3 && b >= 1 && b <= 3){ Wm[a][b] = m[a-1][b-1]; continue; }
          int gi = i0-1+a, gj = j0-1+b;
          Wm[a][b] = (gi >= 0 && gi < NXN && gj >= 0 && gj < NXN) ? pub[gj*NXN + gi] : 0.f;
        }
      #pragma unroll
      for (int di = 0; di < 3; di++)
        #pragma unroll
        for (int dj = 0; dj < 3; dj++)
          STENCIL(Wm, di, dj, n[di][dj]);
    }

    double gamma = sum16_tree(s_gA[it&1]);
    double delta = sum16_tree(s_gB[it&1]);
    if (it == 0) tol = gamma * TOL_REL;
    if (gamma <= tol || !(delta > 0.0)) break;   // uniform across waves

    double beta  = (it == 0) ? 0.0 : gamma / gamma_old;
    double alpha = (it == 0) ? gamma / delta
                             : gamma / (delta - beta * gamma / alpha_old);
    gamma_old = gamma; alpha_old = alpha;
    float bf = (float)beta, af = (float)alpha;

    #pragma unroll
    for (int di = 0; di < 3; di++)
      #pragma unroll
      for (int dj = 0; dj < 3; dj++){
        float zn = n[di][dj] + bf * z[di][dj];  z[di][dj] = zn;   // z = A q
        float sn = w[di][dj] + bf * s[di][dj];  s[di][dj] = sn;   // s = A p
        float uv = invd[di][dj] * r[di][dj];
        float pn = uv + bf * p[di][dj];         p[di][dj] = pn;
        x[di][dj] += af * pn;
        r[di][dj] -= af * sn;
        w[di][dj] -= af * zn;
      }
  }

  __syncthreads();   // all waves done with pub buffers before final publish

  // ---- final u = u0lin + x into s_buf0 ----
  #pragma unroll
  for (int di = 0; di < 3; di++)
    #pragma unroll
    for (int dj = 0; dj < 3; dj++){
      int i = i0+di, j = j0+dj;
      float u;
      if (i == 0) u = 1.f;
      else if (i == NXN-1) u = 0.f;
      else u = 1.f - (float)i*(1.f/95.f) + x[di][dj];
      s_buf0[j*NXN + i] = u;
    }
  __syncthreads();

  // ---- energy: per cell sigma*0.5*(|gradA|^2 + |gradB|^2) ----
  float U[4][4];
  #pragma unroll
  for (int a = 0; a < 4; a++)
    #pragma unroll
    for (int b = 0; b < 4; b++){
      int gi = i0+a, gj = j0+b;
      U[a][b] = (gi < NXN && gj < NXN) ? s_buf0[gj*NXN + gi] : 0.f;
    }
  double ep = 0.0;
  #pragma unroll
  for (int di = 0; di < 3; di++)
    #pragma unroll
    for (int dj = 0; dj < 3; dj++){
      int ci = i0+di, cj = j0+dj;
      if (ci < NCW && cj < NCW){
        float sig = S[di+1][dj+1];
        float u00 = U[di][dj], uE = U[di+1][dj], uN = U[di][dj+1], uNE = U[di+1][dj+1];
        float gxA = uE - u00, gyA = uN - u00;
        float gxB = -2.f*uE + uNE + uN, gyB = uE - uNE;
        ep += (double)(sig * 0.5f * (gxA*gxA + gyA*gyA + gxB*gxB + gyB*gyB));
      }
    }
  {
    double dummy = 0.0;
    dual_warp_red(ep, dummy);
    if (lane == 0) s_gA[0][wid] = ep;
  }
  __syncthreads();
  if (tid == 0) out[0] = (float)sum16_tree(s_gA[0]);
}

extern "C" void kernel_launch(void* const* d_in, const int* in_sizes, int n_in,
                              void* d_out, int out_size, void* d_ws, size_t ws_size,
                              hipStream_t stream){
  (void)d_ws; (void)ws_size; (void)out_size;
  int mi = 0;
  for (int k = 0; k < n_in; k++) if (in_sizes[k] == 9025) { mi = k; break; }
  const float* mask = (const float*)d_in[mi];
  fem_cg_kernel<<<dim3(1), dim3(NTHREADS), 0, stream>>>(mask, (float*)d_out);
}